// Round 2
// baseline (549.199 us; speedup 1.0000x reference)
//
#include <hip/hip_runtime.h>
#include <stdint.h>

// Problem constants (fixed by the reference)
#define Bc 4
#define Sc 2048
#define Dc 768
#define Kc 8192
#define NSc 2
#define Mc (Bc*Sc)                      // 8192 tokens
#define NTILES 64                        // Kc / 128 column tiles
#define EMB_ELEMS ((size_t)Mc*NSc*Dc)   // emb output floats; indices follow

typedef __attribute__((ext_vector_type(8))) __bf16 bf16x8;
typedef __attribute__((ext_vector_type(4))) float f32x4;
typedef __attribute__((ext_vector_type(4))) unsigned short u16x4;

__device__ __forceinline__ unsigned short f2bf(float f){
  unsigned int u = __float_as_uint(f);
  u += 0x7FFFu + ((u >> 16) & 1u);       // round-to-nearest-even
  return (unsigned short)(u >> 16);
}
__device__ __forceinline__ float bf2f(unsigned short h){
  return __uint_as_float(((unsigned int)h) << 16);
}

// ---------------- K0: convert x,w f32 -> bf16 (into ws) ----------------
__global__ __launch_bounds__(256) void k_convert(const float4* __restrict__ x,
                                                 const float4* __restrict__ w,
                                                 u16x4* __restrict__ xb,
                                                 u16x4* __restrict__ wb){
  int i = blockIdx.x * 256 + threadIdx.x;
  float4 v = x[i];
  u16x4 o;
  o.x = f2bf(v.x); o.y = f2bf(v.y); o.z = f2bf(v.z); o.w = f2bf(v.w);
  xb[i] = o;
  v = w[i];
  o.x = f2bf(v.x); o.y = f2bf(v.y); o.z = f2bf(v.z); o.w = f2bf(v.w);
  wb[i] = o;
}

// ---------------- K1: bf16 MFMA GEMM + fused gumbel-max epilogue -------------
// logits[m][k] = sum_d x[m][d]*w[k][d], stored bf16 (row stride 32768 ushorts,
// aliased into the indices output region). Epilogue: per (token, sample,
// 128-col tile) max of (logit_f32 + gumbel) -> stats array in ws.
#define BM 128
#define BN 128
#define BK 32

__global__ __launch_bounds__(256) void k_gemm(const unsigned short* __restrict__ xb,
                                              const unsigned short* __restrict__ wb,
                                              const float* __restrict__ gumbel,
                                              unsigned short* __restrict__ logits,
                                              float* __restrict__ stats){
  __shared__ unsigned short As[BM*BK];   // 8 KB, linear (global_load_lds dest)
  __shared__ unsigned short Bs[BN*BK];   // 8 KB
  __shared__ float smax[NSc][BM][2];     // 2 KB epilogue merge

  const int tid  = threadIdx.x;
  const int lane = tid & 63;
  const int wid  = tid >> 6;             // 4 waves, 2x2 -> each owns 64x64 out
  const int wm   = wid >> 1;
  const int wn   = wid & 1;
  const int bm0  = blockIdx.y * BM;
  const int bn0  = blockIdx.x * BN;

  f32x4 acc[4][4] = {};

  const int srow  = tid >> 2;
  const int scole = (tid & 3) * 8;
  const unsigned short* aS0 = xb + (size_t)(bm0 + srow) * Dc + scole;
  const unsigned short* aS1 = xb + (size_t)(bm0 + 64 + srow) * Dc + scole;
  const unsigned short* bS0 = wb + (size_t)(bn0 + srow) * Dc + scole;
  const unsigned short* bS1 = wb + (size_t)(bn0 + 64 + srow) * Dc + scole;
  unsigned short* aD0 = &As[wid * 512];
  unsigned short* aD1 = &As[2048 + wid * 512];
  unsigned short* bD0 = &Bs[wid * 512];
  unsigned short* bD1 = &Bs[2048 + wid * 512];

  const int fr = lane & 15;
  const int fk = (lane >> 4) * 8;

  for (int kt = 0; kt < Dc; kt += BK) {
    __syncthreads();
    __builtin_amdgcn_global_load_lds((const __attribute__((address_space(1))) void*)(aS0 + kt),
                                     (__attribute__((address_space(3))) void*)aD0, 16, 0, 0);
    __builtin_amdgcn_global_load_lds((const __attribute__((address_space(1))) void*)(aS1 + kt),
                                     (__attribute__((address_space(3))) void*)aD1, 16, 0, 0);
    __builtin_amdgcn_global_load_lds((const __attribute__((address_space(1))) void*)(bS0 + kt),
                                     (__attribute__((address_space(3))) void*)bD0, 16, 0, 0);
    __builtin_amdgcn_global_load_lds((const __attribute__((address_space(1))) void*)(bS1 + kt),
                                     (__attribute__((address_space(3))) void*)bD1, 16, 0, 0);
    __syncthreads();

    bf16x8 a[4], b[4];
    #pragma unroll
    for (int i = 0; i < 4; i++) {
      a[i] = *(const bf16x8*)&As[(wm*64 + i*16 + fr) * BK + fk];
      b[i] = *(const bf16x8*)&Bs[(wn*64 + i*16 + fr) * BK + fk];
    }
    #pragma unroll
    for (int i = 0; i < 4; i++)
      #pragma unroll
      for (int j = 0; j < 4; j++)
        acc[i][j] = __builtin_amdgcn_mfma_f32_16x16x32_bf16(a[i], b[j], acc[i][j], 0, 0, 0);
  }

  // C/D layout: col = lane&15, row = (lane>>4)*4 + reg  (validated in round 1)
  const int crow0 = bm0 + wm*64 + (lane >> 4) * 4;
  const int ccol0 = bn0 + wn*64 + (lane & 15);
  #pragma unroll
  for (int i = 0; i < 4; i++)
    #pragma unroll
    for (int j = 0; j < 4; j++)
      #pragma unroll
      for (int r = 0; r < 4; r++)
        logits[(size_t)(crow0 + i*16 + r) * 32768 + (ccol0 + j*16)] = f2bf(acc[i][j][r]);

  // Fused epilogue: per-token max of (acc + gumbel) over this block's 128 cols.
  #pragma unroll
  for (int s = 0; s < NSc; s++) {
    #pragma unroll
    for (int i = 0; i < 4; i++) {
      #pragma unroll
      for (int r = 0; r < 4; r++) {
        const int trow = wm*64 + i*16 + (lane >> 4)*4 + r;      // token in block
        const float* g = gumbel + ((size_t)(bm0 + trow)*NSc + s)*Kc
                                + bn0 + wn*64 + (lane & 15);
        float m = -1e30f;
        #pragma unroll
        for (int j = 0; j < 4; j++)
          m = fmaxf(m, acc[i][j][r] + g[j*16]);
        #pragma unroll
        for (int off = 1; off <= 8; off <<= 1)
          m = fmaxf(m, __shfl_xor(m, off));                      // 16-lane col group
        if ((lane & 15) == 0) smax[s][trow][wn] = m;
      }
    }
  }
  __syncthreads();
  {
    const int s = tid >> 7, trow = tid & 127;                    // 256 threads cover all
    const float m = fmaxf(smax[s][trow][0], smax[s][trow][1]);
    stats[((size_t)(bm0 + trow)*NSc + s)*NTILES + blockIdx.x] = m;
  }
}

// ---------------- K2: select-lite: suspect-tile argmax + outputs -------------
#define MARGIN 0.125f

__global__ __launch_bounds__(256) void k_select(const unsigned short* logits,   // aliases out_ind!
                                                const float* __restrict__ stats,
                                                const float* __restrict__ gumbel,
                                                const float* __restrict__ x,
                                                const float* __restrict__ w,
                                                const float* __restrict__ emb_tab,
                                                float* __restrict__ out_emb,
                                                float* out_ind){
  const int t   = blockIdx.x;
  const int tid = threadIdx.x;
  const int lane = tid & 63, wid = tid >> 6;

  __shared__ int   cand_k[16];
  __shared__ float cand_g[16];
  __shared__ int   cand_cnt;
  __shared__ int   sel_idx[NSc];

  // ---- decide argmax for BOTH samples before any write (logits alias out_ind)
  for (int s = 0; s < NSc; ++s) {
    if (tid == 0) cand_cnt = 0;
    __syncthreads();

    if (wid == 0) {   // one wave: 64 lanes <-> 64 column tiles
      const float myv = stats[((size_t)t*NSc + s)*NTILES + lane];
      float g = myv;
      #pragma unroll
      for (int off = 32; off; off >>= 1) g = fmaxf(g, __shfl_xor(g, off));
      const float thr = g - MARGIN;
      unsigned long long mask = __ballot(myv >= thr);   // suspect tiles (>=1)
      const unsigned short* lrow = logits + (size_t)t * 32768;
      const float* grow = gumbel + ((size_t)t*NSc + s)*Kc;
      while (mask) {
        const int tile = __ffsll(mask) - 1;
        mask &= mask - 1;
        const int k0 = tile * 128;
        #pragma unroll
        for (int q = 0; q < 2; ++q) {
          const int k = k0 + q*64 + lane;
          const float val = bf2f(lrow[k]) + grow[k];
          if (val >= thr) {
            const int p = atomicAdd(&cand_cnt, 1);
            if (p < 16) cand_k[p] = k;
          }
        }
      }
    }
    __syncthreads();

    const int cnt = min(cand_cnt, 16);
    if (cnt == 1) {
      if (tid == 0) sel_idx[s] = cand_k[0];
    } else {
      // exact refine: wave `wid` takes candidates wid, wid+4, ...
      const float* grow = gumbel + ((size_t)t*NSc + s)*Kc;
      for (int c = wid; c < cnt; c += 4) {
        const int kc = cand_k[c];
        const float* wr = w + (size_t)kc * Dc;
        const float* xr = x + (size_t)t * Dc;
        double accd = 0.0;
        for (int d = lane; d < Dc; d += 64) accd += (double)xr[d] * (double)wr[d];
        #pragma unroll
        for (int off = 32; off; off >>= 1) accd += __shfl_xor(accd, off);
        if (lane == 0) cand_g[c] = (float)accd + grow[kc];
      }
      __syncthreads();
      if (tid == 0) {
        float bg = -1e30f; int bk = Kc;
        for (int c = 0; c < cnt; ++c) {
          const float gg = cand_g[c]; const int kk = cand_k[c];
          if (gg > bg || (gg == bg && kk < bk)) { bg = gg; bk = kk; }
        }
        sel_idx[s] = bk;
      }
    }
    __syncthreads();
  }

  // ---- writes: one-hot indices rows + embedding gathers
  #pragma unroll
  for (int s = 0; s < NSc; ++s) {
    const int idx = sel_idx[s];
    float* irow = out_ind + ((size_t)t*NSc + s)*Kc;
    #pragma unroll
    for (int j = 0; j < 8; ++j) {
      const int k0 = j*1024 + tid*4;
      float4 z = {0.f, 0.f, 0.f, 0.f};
      const int d = idx - k0;
      if (d == 0) z.x = 1.0f; else if (d == 1) z.y = 1.0f;
      else if (d == 2) z.z = 1.0f; else if (d == 3) z.w = 1.0f;
      ((float4*)irow)[j*256 + tid] = z;
    }
    const float* er = emb_tab + (size_t)idx * Dc;
    float* eo = out_emb + ((size_t)t*NSc + s)*Dc;
    for (int d = tid; d < Dc; d += 256) eo[d] = er[d];
  }
}

extern "C" void kernel_launch(void* const* d_in, const int* in_sizes, int n_in,
                              void* d_out, int out_size, void* d_ws, size_t ws_size,
                              hipStream_t stream) {
  const float* x   = (const float*)d_in[0];
  const float* w   = (const float*)d_in[1];
  const float* emb = (const float*)d_in[2];
  const float* gum = (const float*)d_in[3];

  float* out_emb = (float*)d_out;
  float* out_ind = out_emb + EMB_ELEMS;
  unsigned short* logits = (unsigned short*)out_ind;   // token row t at ushort t*32768

  unsigned short* xb = (unsigned short*)d_ws;           // [M][D] bf16 (12.6 MB)
  unsigned short* wb = xb + (size_t)Mc * Dc;            // [K][D] bf16 (12.6 MB)
  float* stats = (float*)(wb + (size_t)Kc * Dc);        // [M][NS][64] f32 (4.2 MB)

  const int n4 = (Mc * Dc) / 4;
  k_convert<<<n4 / 256, 256, 0, stream>>>((const float4*)x, (const float4*)w,
                                          (u16x4*)xb, (u16x4*)wb);
  dim3 gg(Kc / BN, Mc / BM);
  k_gemm<<<gg, 256, 0, stream>>>(xb, wb, gum, logits, stats);
  k_select<<<Mc, 256, 0, stream>>>(logits, stats, gum, x, w, emb, out_emb, out_ind);
}

// Round 3
// 515.289 us; speedup vs baseline: 1.0658x; 1.0658x over previous
//
#include <hip/hip_runtime.h>
#include <stdint.h>

// Problem constants (fixed by the reference)
#define Bc 4
#define Sc 2048
#define Dc 768
#define Kc 8192
#define NSc 2
#define Mc (Bc*Sc)                      // 8192 tokens
#define NTILES 64                        // Kc / 128 column tiles
#define EMB_ELEMS ((size_t)Mc*NSc*Dc)   // emb output floats; indices follow

typedef __attribute__((ext_vector_type(8))) __bf16 bf16x8;
typedef __attribute__((ext_vector_type(4))) float f32x4;
typedef __attribute__((ext_vector_type(4))) unsigned short u16x4;

__device__ __forceinline__ unsigned short f2bf(float f){
  unsigned int u = __float_as_uint(f);
  u += 0x7FFFu + ((u >> 16) & 1u);       // round-to-nearest-even
  return (unsigned short)(u >> 16);
}
__device__ __forceinline__ float bf2f(unsigned short h){
  return __uint_as_float(((unsigned int)h) << 16);
}

// ---------------- K0: convert x,w f32 -> bf16 (into ws) ----------------
__global__ __launch_bounds__(256) void k_convert(const float4* __restrict__ x,
                                                 const float4* __restrict__ w,
                                                 u16x4* __restrict__ xb,
                                                 u16x4* __restrict__ wb){
  int i = blockIdx.x * 256 + threadIdx.x;
  float4 v = x[i];
  u16x4 o;
  o.x = f2bf(v.x); o.y = f2bf(v.y); o.z = f2bf(v.z); o.w = f2bf(v.w);
  xb[i] = o;
  v = w[i];
  o.x = f2bf(v.x); o.y = f2bf(v.y); o.z = f2bf(v.z); o.w = f2bf(v.w);
  wb[i] = o;
}

// ---------------- K1: bf16 MFMA GEMM + fused gumbel-max epilogue -------------
// logits[m][k] = sum_d x[m][d]*w[k][d], stored bf16 (row stride 32768 ushorts,
// aliased into the indices output region). Epilogue: per (token, sample,
// 128-col tile) max of (logit_f32 + gumbel) -> stats array in ws.
// Gumbel is staged through LDS with coalesced float4 loads (round-2's scalar
// scattered loads were the regression).
#define BM 128
#define BN 128
#define BK 32
#define GSTRIDE 132                      // floats per gbuf row (16B-aligned, 2-way banks)

__global__ __launch_bounds__(256) void k_gemm(const unsigned short* __restrict__ xb,
                                              const unsigned short* __restrict__ wb,
                                              const float* __restrict__ gumbel,
                                              unsigned short* __restrict__ logits,
                                              float* __restrict__ stats){
  // 33.8 KB overlay: [As 8KB | Bs 8KB] during K-loop, gbuf[64][132] f32 after.
  __shared__ __align__(16) unsigned char smem[64 * GSTRIDE * 4];
  __shared__ float smax[NSc][BM][2];     // 2 KB epilogue merge (persistent)

  unsigned short* As = (unsigned short*)smem;
  unsigned short* Bs = As + BM * BK;
  float* gbuf = (float*)smem;

  const int tid  = threadIdx.x;
  const int lane = tid & 63;
  const int wid  = tid >> 6;             // 4 waves, 2x2 -> each owns 64x64 out
  const int wm   = wid >> 1;
  const int wn   = wid & 1;
  const int bm0  = blockIdx.y * BM;
  const int bn0  = blockIdx.x * BN;

  f32x4 acc[4][4] = {};

  const int srow  = tid >> 2;
  const int scole = (tid & 3) * 8;
  const unsigned short* aS0 = xb + (size_t)(bm0 + srow) * Dc + scole;
  const unsigned short* aS1 = xb + (size_t)(bm0 + 64 + srow) * Dc + scole;
  const unsigned short* bS0 = wb + (size_t)(bn0 + srow) * Dc + scole;
  const unsigned short* bS1 = wb + (size_t)(bn0 + 64 + srow) * Dc + scole;
  unsigned short* aD0 = &As[wid * 512];
  unsigned short* aD1 = &As[2048 + wid * 512];
  unsigned short* bD0 = &Bs[wid * 512];
  unsigned short* bD1 = &Bs[2048 + wid * 512];

  const int fr = lane & 15;
  const int fk = (lane >> 4) * 8;

  for (int kt = 0; kt < Dc; kt += BK) {
    __syncthreads();
    __builtin_amdgcn_global_load_lds((const __attribute__((address_space(1))) void*)(aS0 + kt),
                                     (__attribute__((address_space(3))) void*)aD0, 16, 0, 0);
    __builtin_amdgcn_global_load_lds((const __attribute__((address_space(1))) void*)(aS1 + kt),
                                     (__attribute__((address_space(3))) void*)aD1, 16, 0, 0);
    __builtin_amdgcn_global_load_lds((const __attribute__((address_space(1))) void*)(bS0 + kt),
                                     (__attribute__((address_space(3))) void*)bD0, 16, 0, 0);
    __builtin_amdgcn_global_load_lds((const __attribute__((address_space(1))) void*)(bS1 + kt),
                                     (__attribute__((address_space(3))) void*)bD1, 16, 0, 0);
    __syncthreads();

    bf16x8 a[4], b[4];
    #pragma unroll
    for (int i = 0; i < 4; i++) {
      a[i] = *(const bf16x8*)&As[(wm*64 + i*16 + fr) * BK + fk];
      b[i] = *(const bf16x8*)&Bs[(wn*64 + i*16 + fr) * BK + fk];
    }
    #pragma unroll
    for (int i = 0; i < 4; i++)
      #pragma unroll
      for (int j = 0; j < 4; j++)
        acc[i][j] = __builtin_amdgcn_mfma_f32_16x16x32_bf16(a[i], b[j], acc[i][j], 0, 0, 0);
  }

  // C/D layout: col = lane&15, row = (lane>>4)*4 + reg  (validated)
  const int crow0 = bm0 + wm*64 + (lane >> 4) * 4;
  const int ccol0 = bn0 + wn*64 + (lane & 15);
  #pragma unroll
  for (int i = 0; i < 4; i++)
    #pragma unroll
    for (int j = 0; j < 4; j++)
      #pragma unroll
      for (int r = 0; r < 4; r++)
        logits[(size_t)(crow0 + i*16 + r) * 32768 + (ccol0 + j*16)] = f2bf(acc[i][j][r]);

  // Fused epilogue: per (token, sample) max of (acc + gumbel) over this
  // block's 128 cols, gumbel staged via LDS in 4 chunks of (sample, 64-token half).
  for (int s = 0; s < NSc; ++s) {
    for (int h = 0; h < 2; ++h) {
      __syncthreads();                   // gbuf free (K-loop reads / prev reduce done)
      {
        const int tw = tid >> 5;         // 0..7
        const int c4 = tid & 31;         // float4 column
        #pragma unroll
        for (int k = 0; k < 8; ++k) {
          const int tok = k*8 + tw;
          const float4 g4 = *(const float4*)(gumbel +
              ((size_t)(bm0 + h*64 + tok) * NSc + s) * Kc + bn0 + c4*4);
          *(float4*)&gbuf[tok * GSTRIDE + c4*4] = g4;
        }
      }
      __syncthreads();
      if (wm == h) {
        #pragma unroll
        for (int i = 0; i < 4; ++i) {
          #pragma unroll
          for (int r = 0; r < 4; ++r) {
            const int tl = i*16 + (lane >> 4)*4 + r;   // token within half
            float m = -1e30f;
            #pragma unroll
            for (int j = 0; j < 4; ++j)
              m = fmaxf(m, acc[i][j][r] + gbuf[tl * GSTRIDE + wn*64 + j*16 + (lane & 15)]);
            #pragma unroll
            for (int off = 1; off <= 8; off <<= 1)
              m = fmaxf(m, __shfl_xor(m, off));        // 16-lane col group
            if ((lane & 15) == 0) smax[s][h*64 + tl][wn] = m;
          }
        }
      }
    }
  }
  __syncthreads();
  {
    const int s = tid >> 7, trow = tid & 127;          // 256 threads cover all
    const float m = fmaxf(smax[s][trow][0], smax[s][trow][1]);
    stats[((size_t)(bm0 + trow)*NSc + s)*NTILES + blockIdx.x] = m;
  }
}

// ---------------- K2: select-lite: suspect-tile argmax + outputs -------------
#define MARGIN 0.125f

__global__ __launch_bounds__(256) void k_select(const unsigned short* logits,   // aliases out_ind!
                                                const float* __restrict__ stats,
                                                const float* __restrict__ gumbel,
                                                const float* __restrict__ x,
                                                const float* __restrict__ w,
                                                const float* __restrict__ emb_tab,
                                                float* __restrict__ out_emb,
                                                float* out_ind){
  const int t   = blockIdx.x;
  const int tid = threadIdx.x;
  const int lane = tid & 63, wid = tid >> 6;

  __shared__ int   cand_k[16];
  __shared__ float cand_g[16];
  __shared__ int   cand_cnt;
  __shared__ int   sel_idx[NSc];

  // ---- decide argmax for BOTH samples before any write (logits alias out_ind)
  for (int s = 0; s < NSc; ++s) {
    if (tid == 0) cand_cnt = 0;
    __syncthreads();

    if (wid == 0) {   // one wave: 64 lanes <-> 64 column tiles
      const float myv = stats[((size_t)t*NSc + s)*NTILES + lane];
      float g = myv;
      #pragma unroll
      for (int off = 32; off; off >>= 1) g = fmaxf(g, __shfl_xor(g, off));
      const float thr = g - MARGIN;
      unsigned long long mask = __ballot(myv >= thr);   // suspect tiles (>=1)
      const unsigned short* lrow = logits + (size_t)t * 32768;
      const float* grow = gumbel + ((size_t)t*NSc + s)*Kc;
      while (mask) {
        const int tile = __ffsll(mask) - 1;
        mask &= mask - 1;
        const int k0 = tile * 128;
        #pragma unroll
        for (int q = 0; q < 2; ++q) {
          const int k = k0 + q*64 + lane;
          const float val = bf2f(lrow[k]) + grow[k];
          if (val >= thr) {
            const int p = atomicAdd(&cand_cnt, 1);
            if (p < 16) cand_k[p] = k;
          }
        }
      }
    }
    __syncthreads();

    const int cnt = min(cand_cnt, 16);
    if (cnt == 1) {
      if (tid == 0) sel_idx[s] = cand_k[0];
    } else {
      // exact refine: wave `wid` takes candidates wid, wid+4, ...
      const float* grow = gumbel + ((size_t)t*NSc + s)*Kc;
      for (int c = wid; c < cnt; c += 4) {
        const int kc = cand_k[c];
        const float* wr = w + (size_t)kc * Dc;
        const float* xr = x + (size_t)t * Dc;
        double accd = 0.0;
        for (int d = lane; d < Dc; d += 64) accd += (double)xr[d] * (double)wr[d];
        #pragma unroll
        for (int off = 32; off; off >>= 1) accd += __shfl_xor(accd, off);
        if (lane == 0) cand_g[c] = (float)accd + grow[kc];
      }
      __syncthreads();
      if (tid == 0) {
        float bg = -1e30f; int bk = Kc;
        for (int c = 0; c < cnt; ++c) {
          const float gg = cand_g[c]; const int kk = cand_k[c];
          if (gg > bg || (gg == bg && kk < bk)) { bg = gg; bk = kk; }
        }
        sel_idx[s] = bk;
      }
    }
    __syncthreads();
  }

  // ---- writes: one-hot indices rows + embedding gathers
  #pragma unroll
  for (int s = 0; s < NSc; ++s) {
    const int idx = sel_idx[s];
    float* irow = out_ind + ((size_t)t*NSc + s)*Kc;
    #pragma unroll
    for (int j = 0; j < 8; ++j) {
      const int k0 = j*1024 + tid*4;
      float4 z = {0.f, 0.f, 0.f, 0.f};
      const int d = idx - k0;
      if (d == 0) z.x = 1.0f; else if (d == 1) z.y = 1.0f;
      else if (d == 2) z.z = 1.0f; else if (d == 3) z.w = 1.0f;
      ((float4*)irow)[j*256 + tid] = z;
    }
    const float* er = emb_tab + (size_t)idx * Dc;
    float* eo = out_emb + ((size_t)t*NSc + s)*Dc;
    for (int d = tid; d < Dc; d += 256) eo[d] = er[d];
  }
}

extern "C" void kernel_launch(void* const* d_in, const int* in_sizes, int n_in,
                              void* d_out, int out_size, void* d_ws, size_t ws_size,
                              hipStream_t stream) {
  const float* x   = (const float*)d_in[0];
  const float* w   = (const float*)d_in[1];
  const float* emb = (const float*)d_in[2];
  const float* gum = (const float*)d_in[3];

  float* out_emb = (float*)d_out;
  float* out_ind = out_emb + EMB_ELEMS;
  unsigned short* logits = (unsigned short*)out_ind;   // token row t at ushort t*32768

  unsigned short* xb = (unsigned short*)d_ws;           // [M][D] bf16 (12.6 MB)
  unsigned short* wb = xb + (size_t)Mc * Dc;            // [K][D] bf16 (12.6 MB)
  float* stats = (float*)(wb + (size_t)Kc * Dc);        // [M][NS][64] f32 (4.2 MB)

  const int n4 = (Mc * Dc) / 4;
  k_convert<<<n4 / 256, 256, 0, stream>>>((const float4*)x, (const float4*)w,
                                          (u16x4*)xb, (u16x4*)wb);
  dim3 gg(Kc / BN, Mc / BM);
  k_gemm<<<gg, 256, 0, stream>>>(xb, wb, gum, logits, stats);
  k_select<<<Mc, 256, 0, stream>>>(logits, stats, gum, x, w, emb, out_emb, out_ind);
}